// Round 1
// baseline (609.599 us; speedup 1.0000x reference)
//
#include <hip/hip_runtime.h>
#include <hip/hip_bf16.h>

#define DIM   1024
#define NVEC  128
#define BROWS 32768

typedef short s16x8 __attribute__((ext_vector_type(8)));
typedef float f32x4 __attribute__((ext_vector_type(4)));

__device__ __forceinline__ unsigned short f2bf(float f) {
    union { float f; unsigned int u; } c; c.f = f;
    unsigned int u = c.u;
    u += 0x7fffu + ((u >> 16) & 1u);   // round-to-nearest-even
    return (unsigned short)(u >> 16);
}

// ---------------------------------------------------------------------------
// K0: per-column normalize v; write VnT (fp32, [NVEC][DIM]) and VnT16 (bf16)
// ---------------------------------------------------------------------------
__global__ __launch_bounds__(256) void k_norm(const float* __restrict__ v,
                                              float* __restrict__ VnT,
                                              unsigned short* __restrict__ VnT16) {
    int i = blockIdx.x;          // which reflection vector
    int t = threadIdx.x;         // 256 threads
    __shared__ float red[4];
    float ss = 0.f;
    for (int d = t; d < DIM; d += 256) {
        float val = v[d * NVEC + i];
        ss += val * val;
    }
    for (int o = 32; o > 0; o >>= 1) ss += __shfl_down(ss, o, 64);
    if ((t & 63) == 0) red[t >> 6] = ss;
    __syncthreads();
    if (t == 0) red[0] = rsqrtf(red[0] + red[1] + red[2] + red[3]);
    __syncthreads();
    float rn = red[0];
    for (int d = t; d < DIM; d += 256) {
        float val = v[d * NVEC + i] * rn;
        VnT[i * DIM + d]   = val;
        VnT16[i * DIM + d] = f2bf(val);
    }
}

// ---------------------------------------------------------------------------
// K1: Gram matrix G[i][j] = <v_i, v_j>  (fp32, rows of VnT are coalesced)
// ---------------------------------------------------------------------------
__global__ __launch_bounds__(256) void k_gram(const float* __restrict__ VnT,
                                              float* __restrict__ G) {
    int i = blockIdx.x;
    int t = threadIdx.x, w = t >> 6, l = t & 63;
    float ri[16];
#pragma unroll
    for (int c = 0; c < 16; c++) ri[c] = VnT[i * DIM + c * 64 + l];
    for (int j = w; j < NVEC; j += 4) {
        const float* rj = VnT + j * DIM;
        float s = 0.f;
#pragma unroll
        for (int c = 0; c < 16; c++) s += ri[c] * rj[c * 64 + l];
        for (int o = 32; o > 0; o >>= 1) s += __shfl_down(s, o, 64);
        if (l == 0) G[i * NVEC + j] = s;
    }
}

// ---------------------------------------------------------------------------
// K2: T recurrence (larft): T[0:k,k] = -2 * T[0:k,0:k] @ G[0:k,k], T[k,k]=2
// single block, 512 threads: thread = (row i = t>>2, split s = t&3)
// ---------------------------------------------------------------------------
__global__ __launch_bounds__(512) void k_tmat(const float* __restrict__ G,
                                              float* __restrict__ Tout) {
    __shared__ float T[NVEC * NVEC];          // 64 KB
    int t = threadIdx.x;
    int i = t >> 2, s = t & 3;
    for (int idx = t; idx < NVEC * NVEC; idx += 512) T[idx] = 0.f;
    __syncthreads();
    for (int k = 0; k < NVEC; k++) {
        float p = 0.f;
        if (i < k) {
            int len = k - i;
            int chunk = (len + 3) >> 2;
            int j0 = i + s * chunk;
            int j1 = min(j0 + chunk, k);
            for (int j = j0; j < j1; j++) p += T[i * NVEC + j] * G[j * NVEC + k];
        }
        // combine 4 partials within the wave (lanes 4i..4i+3)
        p += __shfl_down(p, 2, 64);
        p += __shfl_down(p, 1, 64);
        if (s == 0) {
            if (i < k)       T[i * NVEC + k] = -2.f * p;
            else if (i == k) T[k * NVEC + k] = 2.f;
        }
        __syncthreads();
    }
    for (int idx = t; idx < NVEC * NVEC; idx += 512) Tout[idx] = T[idx];
}

// ---------------------------------------------------------------------------
// K3: W[d][i] = sum_{j>=i} Vn[d][j] * T[i][j]   (W = V T^T), store bf16
// grid = DIM blocks, NVEC threads (thread = output column i)
// ---------------------------------------------------------------------------
__global__ __launch_bounds__(NVEC) void k_wmat(const float* __restrict__ VnT,
                                               const float* __restrict__ T,
                                               unsigned short* __restrict__ W16) {
    int d = blockIdx.x;
    int i = threadIdx.x;
    float s = 0.f;
    for (int j = i; j < NVEC; j++) s += VnT[j * DIM + d] * T[i * NVEC + j];
    W16[d * NVEC + i] = f2bf(s);
}

// ---------------------------------------------------------------------------
// K4: Y = x @ Vn  (M=32768, N=128, K=1024), bf16 MFMA, store Y bf16
// block: 256 thr (4 waves), tile BM=64 x N=128, BK=64
// ---------------------------------------------------------------------------
#define BK4  64
#define LDA4 72    // 64 + 8 pad (bf16 elems)
#define LDB4 72

__global__ __launch_bounds__(256) void k_ygemm(const float* __restrict__ x,
                                               const unsigned short* __restrict__ VnT16,
                                               unsigned short* __restrict__ Y16) {
    __shared__ unsigned short As[64 * LDA4];
    __shared__ unsigned short Bs[NVEC * LDB4];
    int t = threadIdx.x;
    int r0 = blockIdx.x * 64;
    int w = t >> 6, l = t & 63, q = l >> 4, lm = l & 15;

    f32x4 acc[8];
#pragma unroll
    for (int n = 0; n < 8; n++) acc[n] = (f32x4){0.f, 0.f, 0.f, 0.f};

    for (int k0 = 0; k0 < DIM; k0 += BK4) {
        __syncthreads();
        {   // stage A: 64 rows x 64 k, fp32 -> bf16.  thread: row=t>>2, seg=t&3
            int row = t >> 2, seg = t & 3;
            const float4* src = (const float4*)(x + (size_t)(r0 + row) * DIM + k0);
#pragma unroll
            for (int jj = 0; jj < 4; jj++) {
                float4 f = src[seg + jj * 4];          // cols seg*4 + jj*16 (coalesced)
                ushort4 h;
                h.x = f2bf(f.x); h.y = f2bf(f.y); h.z = f2bf(f.z); h.w = f2bf(f.w);
                *(ushort4*)(As + row * LDA4 + seg * 4 + jj * 16) = h;
            }
        }
        {   // stage B: VnT16 rows n=0..127, cols k0..k0+63. thread: row=t>>1, half=t&1
            int row = t >> 1, half = t & 1;
            const uint4* src = (const uint4*)(VnT16 + (size_t)row * DIM + k0 + half * 32);
            uint4* dst = (uint4*)(Bs + row * LDB4 + half * 32);
#pragma unroll
            for (int jj = 0; jj < 4; jj++) dst[jj] = src[jj];
        }
        __syncthreads();

        int arow = w * 16 + lm;
#pragma unroll
        for (int kk = 0; kk < BK4; kk += 32) {
            s16x8 a = *(const s16x8*)(As + arow * LDA4 + kk + q * 8);
#pragma unroll
            for (int nt = 0; nt < 8; nt++) {
                s16x8 b = *(const s16x8*)(Bs + (nt * 16 + lm) * LDB4 + kk + q * 8);
                acc[nt] = __builtin_amdgcn_mfma_f32_16x16x32_bf16(a, b, acc[nt], 0, 0, 0);
            }
        }
    }
    // epilogue: C/D layout col=lane&15, row=quad*4+reg
    int orow = r0 + w * 16 + q * 4;
#pragma unroll
    for (int nt = 0; nt < 8; nt++) {
        int col = nt * 16 + lm;
#pragma unroll
        for (int r = 0; r < 4; r++)
            Y16[(size_t)(orow + r) * NVEC + col] = f2bf(acc[nt][r]);
    }
}

// ---------------------------------------------------------------------------
// K5: out = x - Y @ W^T + b  (M=32768, N=1024, K=128), bf16 MFMA
// block: 256 thr, tile BM=64 x BN=128, full K=128 staged once
// ---------------------------------------------------------------------------
#define LDA5 136   // 128 + 8 pad
#define LDB5 136

__global__ __launch_bounds__(256) void k_outgemm(const unsigned short* __restrict__ Y16,
                                                 const unsigned short* __restrict__ W16,
                                                 const float* __restrict__ x,
                                                 const float* __restrict__ bias,
                                                 float* __restrict__ out) {
    __shared__ unsigned short As[64 * LDA5];
    __shared__ unsigned short Bs[NVEC * LDB5];
    int t = threadIdx.x;
    int r0 = blockIdx.x * 64;
    int c0 = blockIdx.y * 128;
    int w = t >> 6, l = t & 63, q = l >> 4, lm = l & 15;

    {   // stage A: Y rows r0..r0+63, all 128 cols (bf16). thread: row=t>>2, seg=t&3
        int row = t >> 2, seg = t & 3;
        const uint4* src = (const uint4*)(Y16 + (size_t)(r0 + row) * NVEC + seg * 32);
        uint4* dst = (uint4*)(As + row * LDA5 + seg * 32);
#pragma unroll
        for (int jj = 0; jj < 4; jj++) dst[jj] = src[jj];
    }
    {   // stage B: W rows d=c0..c0+127, all 128 cols. thread: row=t>>1, half=t&1
        int row = t >> 1, half = t & 1;
        const uint4* src = (const uint4*)(W16 + (size_t)(c0 + row) * NVEC + half * 64);
        uint4* dst = (uint4*)(Bs + row * LDB5 + half * 64);
#pragma unroll
        for (int jj = 0; jj < 8; jj++) dst[jj] = src[jj];
    }
    __syncthreads();

    f32x4 acc[8];
#pragma unroll
    for (int n = 0; n < 8; n++) acc[n] = (f32x4){0.f, 0.f, 0.f, 0.f};

    int arow = w * 16 + lm;
#pragma unroll
    for (int kk = 0; kk < NVEC; kk += 32) {
        s16x8 a = *(const s16x8*)(As + arow * LDA5 + kk + q * 8);
#pragma unroll
        for (int nt = 0; nt < 8; nt++) {
            s16x8 b = *(const s16x8*)(Bs + (nt * 16 + lm) * LDB5 + kk + q * 8);
            acc[nt] = __builtin_amdgcn_mfma_f32_16x16x32_bf16(a, b, acc[nt], 0, 0, 0);
        }
    }

    // epilogue: out = x - acc + b
    int orow = r0 + w * 16 + q * 4;
#pragma unroll
    for (int nt = 0; nt < 8; nt++) {
        int col = c0 + nt * 16 + lm;
        float bv = bias[col];
#pragma unroll
        for (int r = 0; r < 4; r++) {
            size_t idx = (size_t)(orow + r) * DIM + col;
            out[idx] = x[idx] - acc[nt][r] + bv;
        }
    }
}

// ---------------------------------------------------------------------------
extern "C" void kernel_launch(void* const* d_in, const int* in_sizes, int n_in,
                              void* d_out, int out_size, void* d_ws, size_t ws_size,
                              hipStream_t stream) {
    const float* x    = (const float*)d_in[0];
    const float* v    = (const float*)d_in[1];
    const float* bias = (const float*)d_in[2];
    float* out = (float*)d_out;

    char* ws = (char*)d_ws;
    float*          VnT   = (float*)(ws);                    // 512 KB  [NVEC][DIM] fp32
    unsigned short* VnT16 = (unsigned short*)(ws + 524288);  // 256 KB  [NVEC][DIM] bf16
    float*          G     = (float*)(ws + 786432);           // 64 KB   [NVEC][NVEC]
    float*          T     = (float*)(ws + 851968);           // 64 KB   [NVEC][NVEC]
    unsigned short* W16   = (unsigned short*)(ws + 917504);  // 256 KB  [DIM][NVEC] bf16
    unsigned short* Y16   = (unsigned short*)(ws + 1179648); // 8 MB    [BROWS][NVEC] bf16

    k_norm<<<NVEC, 256, 0, stream>>>(v, VnT, VnT16);
    k_gram<<<NVEC, 256, 0, stream>>>(VnT, G);
    k_tmat<<<1, 512, 0, stream>>>(G, T);
    k_wmat<<<DIM, NVEC, 0, stream>>>(VnT, T, W16);
    k_ygemm<<<BROWS / 64, 256, 0, stream>>>(x, VnT16, Y16);
    k_outgemm<<<dim3(BROWS / 64, DIM / 128), 256, 0, stream>>>(Y16, W16, x, bias, out);
}

// Round 3
// 411.809 us; speedup vs baseline: 1.4803x; 1.4803x over previous
//
#include <hip/hip_runtime.h>
#include <hip/hip_bf16.h>

#define DIM   1024
#define NVEC  128
#define BROWS 32768

typedef short s16x8 __attribute__((ext_vector_type(8)));
typedef float f32x4 __attribute__((ext_vector_type(4)));

__device__ __forceinline__ unsigned short f2bf(float f) {
    union { float f; unsigned int u; } c; c.f = f;
    unsigned int u = c.u;
    u += 0x7fffu + ((u >> 16) & 1u);   // round-to-nearest-even
    return (unsigned short)(u >> 16);
}

// ---------------------------------------------------------------------------
// K0: per-column normalize v; write VnT (fp32, [NVEC][DIM]) and VnT16 (bf16)
// ---------------------------------------------------------------------------
__global__ __launch_bounds__(256) void k_norm(const float* __restrict__ v,
                                              float* __restrict__ VnT,
                                              unsigned short* __restrict__ VnT16) {
    int i = blockIdx.x;          // which reflection vector
    int t = threadIdx.x;         // 256 threads
    __shared__ float red[4];
    float ss = 0.f;
    for (int d = t; d < DIM; d += 256) {
        float val = v[d * NVEC + i];
        ss += val * val;
    }
    for (int o = 32; o > 0; o >>= 1) ss += __shfl_down(ss, o, 64);
    if ((t & 63) == 0) red[t >> 6] = ss;
    __syncthreads();
    if (t == 0) red[0] = rsqrtf(red[0] + red[1] + red[2] + red[3]);
    __syncthreads();
    float rn = red[0];
    for (int d = t; d < DIM; d += 256) {
        float val = v[d * NVEC + i] * rn;
        VnT[i * DIM + d]   = val;
        VnT16[i * DIM + d] = f2bf(val);
    }
}

// ---------------------------------------------------------------------------
// K1: Gram matrix G[i][j] = <v_i, v_j>  (fp32, rows of VnT are coalesced)
// ---------------------------------------------------------------------------
__global__ __launch_bounds__(256) void k_gram(const float* __restrict__ VnT,
                                              float* __restrict__ G) {
    int i = blockIdx.x;
    int t = threadIdx.x, w = t >> 6, l = t & 63;
    float ri[16];
#pragma unroll
    for (int c = 0; c < 16; c++) ri[c] = VnT[i * DIM + c * 64 + l];
    for (int j = w; j < NVEC; j += 4) {
        const float* rj = VnT + j * DIM;
        float s = 0.f;
#pragma unroll
        for (int c = 0; c < 16; c++) s += ri[c] * rj[c * 64 + l];
        for (int o = 32; o > 0; o >>= 1) s += __shfl_down(s, o, 64);
        if (l == 0) G[i * NVEC + j] = s;
    }
}

// ---------------------------------------------------------------------------
// K2: T = R^{-1}, R = 0.5*I + strict_upper(G)   (tau=2 Householder larft)
// Parallel blocked triangular inversion. LDS = EXACTLY 64 KB (Ts only):
//  - diag 16x16 inverses: per-thread REGISTER back-substitution (unrolled)
//  - combine levels L=16,32,64 processed in 16-row panels top-down:
//      M16 = Ainv[panel,:] * B   then   B[panel,:] = -M16 * Cinv
//    M16 lives in the dead strict-lower triangle of Ts (rows 64..79, cols
//    0..63) — never touched by triangular reads/writes (all have col>=row
//    superblock base). Upper-tri Ainv => later panels read only
//    not-yet-overwritten B rows.
// ---------------------------------------------------------------------------
__global__ __launch_bounds__(256) void k_tinv(const float* __restrict__ G,
                                              float* __restrict__ Tout) {
    __shared__ __align__(16) float Ts[NVEC * NVEC];   // 65536 B exactly
    int t = threadIdx.x;

    // phase 0: R into LDS (0.5 on diag, zeros below)
    {
        int i = t >> 1, jb = (t & 1) * 64;
        for (int j = jb; j < jb + 64; j++) {
            float val = 0.f;
            if (j > i)       val = G[i * NVEC + j];
            else if (j == i) val = 0.5f;
            Ts[i * NVEC + j] = val;
        }
    }
    __syncthreads();

    // phase 1: invert 8 diagonal 16x16 blocks; thread t<128: blk=t>>4, col c=t&15
    {
        int blk = t >> 4, c = t & 15, rb = blk * 16;
        float xs[16];
        if (t < 128) {
#pragma unroll
            for (int jj = 0; jj < 16; jj++) xs[jj] = (jj == c) ? 2.f : 0.f;
#pragma unroll
            for (int i = 14; i >= 0; i--) {
                float s = 0.f;
#pragma unroll
                for (int j = i + 1; j < 16; j++)
                    s += Ts[(rb + i) * NVEC + rb + j] * xs[j];   // xs[j]=0 for j>c
                if (i < c) xs[i] = -2.f * s;
            }
        }
        __syncthreads();           // all reads of original diag blocks done
        if (t < 128) {
#pragma unroll
            for (int i = 0; i < 16; i++)
                if (i <= c) Ts[(rb + i) * NVEC + rb + c] = xs[i];  // keep sub-diag zeros
        }
        __syncthreads();
    }

    // phase 2: combine levels. 256 vec4-tasks per panel sub-phase (1/thread).
#pragma unroll
    for (int L = 16; L <= 64; L <<= 1) {
        int tpp = L << 2;                 // vec4 tasks per pair = 16*L/4
        int p   = t / tpp;                // pair id
        int rem = t % tpp;
        int r   = rem / (L >> 2);         // panel-local row 0..15
        int c0  = (rem % (L >> 2)) << 2;  // vec4 col base within block
        int a0  = p * (L << 1), b0 = a0 + L;
        int npanel = L >> 4;
        for (int pi = 0; pi < npanel; pi++) {
            int gr = a0 + pi * 16 + r;    // global A-side row
            // a: M[r][p*L + c0..+3] = sum_{k >= pi*16+r} Ainv[gr][a0+k] * B[a0+k][b0+c0..]
            f32x4 acc = {0.f, 0.f, 0.f, 0.f};
            for (int k = pi * 16 + r; k < L; k++)
                acc += Ts[gr * NVEC + a0 + k] *
                       *(const f32x4*)&Ts[(a0 + k) * NVEC + b0 + c0];
            *(f32x4*)&Ts[(64 + r) * NVEC + p * L + c0] = acc;
            __syncthreads();
            // b: B[gr][b0+c0..] = -sum_{k <= c0+3} M[r][p*L+k] * Cinv[b0+k][b0+c0..]
            //    (k>col terms vanish: sub-diag zeros inside diag 16-blocks)
            f32x4 acc2 = {0.f, 0.f, 0.f, 0.f};
            for (int k = 0; k <= c0 + 3; k++)
                acc2 += Ts[(64 + r) * NVEC + p * L + k] *
                        *(const f32x4*)&Ts[(b0 + k) * NVEC + b0 + c0];
            *(f32x4*)&Ts[gr * NVEC + b0 + c0] = -acc2;
            __syncthreads();
        }
    }

    // write out (explicit zeros below diag: lower triangle holds M scratch)
    for (int idx = t; idx < NVEC * NVEC; idx += 256) {
        int i = idx >> 7, j = idx & 127;
        Tout[idx] = (j >= i) ? Ts[idx] : 0.f;
    }
}

// ---------------------------------------------------------------------------
// K3: W[d][i] = sum_{j>=i} Vn[d][j] * T[i][j]   (W = V T^T), store bf16
// ---------------------------------------------------------------------------
__global__ __launch_bounds__(NVEC) void k_wmat(const float* __restrict__ VnT,
                                               const float* __restrict__ T,
                                               unsigned short* __restrict__ W16) {
    int d = blockIdx.x;
    int i = threadIdx.x;
    float s = 0.f;
    for (int j = i; j < NVEC; j++) s += VnT[j * DIM + d] * T[i * NVEC + j];
    W16[d * NVEC + i] = f2bf(s);
}

// ---------------------------------------------------------------------------
// K4: Y = x @ Vn  (M=32768, N=128, K=1024), bf16 MFMA, store Y bf16
// ---------------------------------------------------------------------------
#define BK4  64
#define LDA4 72    // 64 + 8 pad (bf16 elems)
#define LDB4 72

__global__ __launch_bounds__(256) void k_ygemm(const float* __restrict__ x,
                                               const unsigned short* __restrict__ VnT16,
                                               unsigned short* __restrict__ Y16) {
    __shared__ unsigned short As[64 * LDA4];
    __shared__ unsigned short Bs[NVEC * LDB4];
    int t = threadIdx.x;
    int r0 = blockIdx.x * 64;
    int w = t >> 6, l = t & 63, q = l >> 4, lm = l & 15;

    f32x4 acc[8];
#pragma unroll
    for (int n = 0; n < 8; n++) acc[n] = (f32x4){0.f, 0.f, 0.f, 0.f};

    for (int k0 = 0; k0 < DIM; k0 += BK4) {
        __syncthreads();
        {   // stage A: 64 rows x 64 k, fp32 -> bf16.  thread: row=t>>2, seg=t&3
            int row = t >> 2, seg = t & 3;
            const float4* src = (const float4*)(x + (size_t)(r0 + row) * DIM + k0);
#pragma unroll
            for (int jj = 0; jj < 4; jj++) {
                float4 f = src[seg + jj * 4];          // cols seg*4 + jj*16 (coalesced)
                ushort4 h;
                h.x = f2bf(f.x); h.y = f2bf(f.y); h.z = f2bf(f.z); h.w = f2bf(f.w);
                *(ushort4*)(As + row * LDA4 + seg * 4 + jj * 16) = h;
            }
        }
        {   // stage B: VnT16 rows n=0..127, cols k0..k0+63. thread: row=t>>1, half=t&1
            int row = t >> 1, half = t & 1;
            const uint4* src = (const uint4*)(VnT16 + (size_t)row * DIM + k0 + half * 32);
            uint4* dst = (uint4*)(Bs + row * LDB4 + half * 32);
#pragma unroll
            for (int jj = 0; jj < 4; jj++) dst[jj] = src[jj];
        }
        __syncthreads();

        int arow = w * 16 + lm;
#pragma unroll
        for (int kk = 0; kk < BK4; kk += 32) {
            s16x8 a = *(const s16x8*)(As + arow * LDA4 + kk + q * 8);
#pragma unroll
            for (int nt = 0; nt < 8; nt++) {
                s16x8 b = *(const s16x8*)(Bs + (nt * 16 + lm) * LDB4 + kk + q * 8);
                acc[nt] = __builtin_amdgcn_mfma_f32_16x16x32_bf16(a, b, acc[nt], 0, 0, 0);
            }
        }
    }
    // epilogue: C/D layout col=lane&15, row=quad*4+reg
    int orow = r0 + w * 16 + q * 4;
#pragma unroll
    for (int nt = 0; nt < 8; nt++) {
        int col = nt * 16 + lm;
#pragma unroll
        for (int r = 0; r < 4; r++)
            Y16[(size_t)(orow + r) * NVEC + col] = f2bf(acc[nt][r]);
    }
}

// ---------------------------------------------------------------------------
// K5: out = x - Y @ W^T + b  (M=32768, N=1024, K=128), bf16 MFMA
// ---------------------------------------------------------------------------
#define LDA5 136   // 128 + 8 pad
#define LDB5 136

__global__ __launch_bounds__(256) void k_outgemm(const unsigned short* __restrict__ Y16,
                                                 const unsigned short* __restrict__ W16,
                                                 const float* __restrict__ x,
                                                 const float* __restrict__ bias,
                                                 float* __restrict__ out) {
    __shared__ unsigned short As[64 * LDA5];
    __shared__ unsigned short Bs[NVEC * LDB5];
    int t = threadIdx.x;
    int r0 = blockIdx.x * 64;
    int c0 = blockIdx.y * 128;
    int w = t >> 6, l = t & 63, q = l >> 4, lm = l & 15;

    {   // stage A: Y rows r0..r0+63, all 128 cols (bf16). thread: row=t>>2, seg=t&3
        int row = t >> 2, seg = t & 3;
        const uint4* src = (const uint4*)(Y16 + (size_t)(r0 + row) * NVEC + seg * 32);
        uint4* dst = (uint4*)(As + row * LDA5 + seg * 32);
#pragma unroll
        for (int jj = 0; jj < 4; jj++) dst[jj] = src[jj];
    }
    {   // stage B: W rows d=c0..c0+127, all 128 cols. thread: row=t>>1, half=t&1
        int row = t >> 1, half = t & 1;
        const uint4* src = (const uint4*)(W16 + (size_t)(c0 + row) * NVEC + half * 64);
        uint4* dst = (uint4*)(Bs + row * LDB5 + half * 64);
#pragma unroll
        for (int jj = 0; jj < 8; jj++) dst[jj] = src[jj];
    }
    __syncthreads();

    f32x4 acc[8];
#pragma unroll
    for (int n = 0; n < 8; n++) acc[n] = (f32x4){0.f, 0.f, 0.f, 0.f};

    int arow = w * 16 + lm;
#pragma unroll
    for (int kk = 0; kk < NVEC; kk += 32) {
        s16x8 a = *(const s16x8*)(As + arow * LDA5 + kk + q * 8);
#pragma unroll
        for (int nt = 0; nt < 8; nt++) {
            s16x8 b = *(const s16x8*)(Bs + (nt * 16 + lm) * LDB5 + kk + q * 8);
            acc[nt] = __builtin_amdgcn_mfma_f32_16x16x32_bf16(a, b, acc[nt], 0, 0, 0);
        }
    }

    // epilogue: out = x - acc + b
    int orow = r0 + w * 16 + q * 4;
#pragma unroll
    for (int nt = 0; nt < 8; nt++) {
        int col = c0 + nt * 16 + lm;
        float bv = bias[col];
#pragma unroll
        for (int r = 0; r < 4; r++) {
            size_t idx = (size_t)(orow + r) * DIM + col;
            out[idx] = x[idx] - acc[nt][r] + bv;
        }
    }
}

// ---------------------------------------------------------------------------
extern "C" void kernel_launch(void* const* d_in, const int* in_sizes, int n_in,
                              void* d_out, int out_size, void* d_ws, size_t ws_size,
                              hipStream_t stream) {
    const float* x    = (const float*)d_in[0];
    const float* v    = (const float*)d_in[1];
    const float* bias = (const float*)d_in[2];
    float* out = (float*)d_out;

    char* ws = (char*)d_ws;
    float*          VnT   = (float*)(ws);                    // 512 KB  [NVEC][DIM] fp32
    unsigned short* VnT16 = (unsigned short*)(ws + 524288);  // 256 KB  [NVEC][DIM] bf16
    float*          G     = (float*)(ws + 786432);           // 64 KB   [NVEC][NVEC]
    float*          T     = (float*)(ws + 851968);           // 64 KB   [NVEC][NVEC]
    unsigned short* W16   = (unsigned short*)(ws + 917504);  // 256 KB  [DIM][NVEC] bf16
    unsigned short* Y16   = (unsigned short*)(ws + 1179648); // 8 MB    [BROWS][NVEC] bf16

    k_norm<<<NVEC, 256, 0, stream>>>(v, VnT, VnT16);
    k_gram<<<NVEC, 256, 0, stream>>>(VnT, G);
    k_tinv<<<1, 256, 0, stream>>>(G, T);
    k_wmat<<<DIM, NVEC, 0, stream>>>(VnT, T, W16);
    k_ygemm<<<BROWS / 64, 256, 0, stream>>>(x, VnT16, Y16);
    k_outgemm<<<dim3(BROWS / 64, DIM / 128), 256, 0, stream>>>(Y16, W16, x, bias, out);
}